// Round 22
// baseline (77.587 us; speedup 1.0000x reference)
//
#include <hip/hip_runtime.h>
#include <hip/hip_bf16.h>
#include <hip/hip_fp16.h>

#define NN 100000
#define EE 1600000
#define ET (EE + NN)            // edges incl. self loops
#define HID 64
#define NEG 0.2f
#define NBUK 391                // ceil(NN/256) buckets of 256 dst nodes
#define SCT_TILE 8192           // edges per block in scatter phase (1024 thr x 8)
#define BUKCAP 8192             // padded per-bucket capacity (mean 4352, sigma~66)

__device__ __forceinline__ float uh(unsigned u) {
    __half_raw r; r.x = (unsigned short)(u & 0xFFFF);
    return __half2float(__half(r));
}
__device__ __forceinline__ unsigned f2h(float f) {
    __half h = __float2half_rn(f);
    __half_raw r = *reinterpret_cast<__half_raw*>(&h);
    return (unsigned)r.x;
}

#define NSCT ((ET + SCT_TILE - 1) / SCT_TILE)   // 208 scatter-role blocks
#define NPROJB ((NN + 31) / 32)                 // 3125 proj-role blocks (32 nodes each)

// ---------------- merged front kernel: scatter role (blocks < NSCT) + proj role ----------------
__global__ __launch_bounds__(1024) void k_front(const float* __restrict__ x,
                                                const float* __restrict__ W1,
                                                const float* __restrict__ a_src1,
                                                const float* __restrict__ a_dst1,
                                                const int* __restrict__ ei,
                                                unsigned* __restrict__ rec,
                                                float* __restrict__ sd1,
                                                int* __restrict__ bcur,
                                                unsigned* __restrict__ pairs) {
    __shared__ unsigned sp[SCT_TILE];
    __shared__ unsigned short bid[SCT_TILE];
    __shared__ int cnt_[NBUK], loc[NBUK], cur[NBUK];
    __shared__ int wsum[16];
    int tid = threadIdx.x;

    if (blockIdx.x >= NSCT) {
        // ---- proj role: 16 waves x 2 nodes = 32 nodes per block ----
        int p = blockIdx.x - NSCT;
        int wid  = tid >> 6;
        int half = (tid >> 5) & 1, li = tid & 31;
        int n = p * 32 + wid * 2 + half;
        if (n >= NN) return;
        float xv[5];
        float h0 = 0.f, h1 = 0.f;
#pragma unroll
        for (int k = 0; k < 5; ++k) {
            xv[k] = x[n * 5 + k];
            h0 += xv[k] * W1[k * HID + li];
            h1 += xv[k] * W1[k * HID + li + 32];
        }
        float a = h0 * a_src1[li] + h1 * a_src1[li + 32];
        float b = h0 * a_dst1[li] + h1 * a_dst1[li + 32];
#pragma unroll
        for (int o = 1; o <= 16; o <<= 1) { a += __shfl_xor(a, o); b += __shfl_xor(b, o); }
        if (li == 0) {
            sd1[n] = b;
            uint4 rv;
            rv.x = __float_as_uint(a);
            rv.y = f2h(xv[0]) | (f2h(xv[1]) << 16);
            rv.z = f2h(xv[2]) | (f2h(xv[3]) << 16);
            rv.w = f2h(xv[4]);
            *(uint4*)(rec + (size_t)n * 4) = rv;
        }
        return;
    }

    // ---- scatter role ----
    int wid = tid >> 6, lane = tid & 63;
    int base = blockIdx.x * SCT_TILE;
    int tilecnt = ET - base; if (tilecnt > SCT_TILE) tilecnt = SCT_TILE;

    for (int i = tid; i < NBUK; i += 1024) cnt_[i] = 0;
    __syncthreads();
    int sreg[8], dreg[8], rreg[8];
#pragma unroll
    for (int it = 0; it < 2; ++it) {
        int i = base + (it * 1024 + tid) * 4;
        if (i + 3 < EE) {
            const int4 sv = *(const int4*)(ei + i);
            const int4 dv = *(const int4*)(ei + EE + i);
            sreg[it*4+0] = sv.x; sreg[it*4+1] = sv.y; sreg[it*4+2] = sv.z; sreg[it*4+3] = sv.w;
            dreg[it*4+0] = dv.x; dreg[it*4+1] = dv.y; dreg[it*4+2] = dv.z; dreg[it*4+3] = dv.w;
        } else {
#pragma unroll
            for (int k = 0; k < 4; ++k) {
                int idx = i + k;
                if (idx < EE)      { sreg[it*4+k] = ei[idx];  dreg[it*4+k] = ei[EE + idx]; }
                else if (idx < ET) { sreg[it*4+k] = idx - EE; dreg[it*4+k] = idx - EE; }
                else               { dreg[it*4+k] = -1; }
            }
        }
#pragma unroll
        for (int k = 0; k < 4; ++k)
            if (dreg[it*4+k] >= 0) rreg[it*4+k] = atomicAdd(&cnt_[dreg[it*4+k] >> 8], 1);
    }
    __syncthreads();
    int b0 = tid * 4;
    int s0 = 0;
    if (b0 < NBUK)
        for (int k = 0; k < 4 && b0 + k < NBUK; ++k) s0 += cnt_[b0 + k];
    int incl = s0;
#pragma unroll
    for (int o = 1; o < 64; o <<= 1) {
        int t = __shfl(incl, (lane - o) & 63);
        if (lane >= o) incl += t;
    }
    if (lane == 63) wsum[wid] = incl;
    __syncthreads();
    int wpref = 0;
    for (int w = 0; w < wid; ++w) wpref += wsum[w];
    if (b0 < NBUK) {
        int run = wpref + incl - s0;
        for (int k = 0; k < 4 && b0 + k < NBUK; ++k) {
            loc[b0 + k] = run;
            run += cnt_[b0 + k];
        }
    }
    __syncthreads();
    for (int i = tid; i < NBUK; i += 1024) {
        int c = cnt_[i];
        cur[i] = c ? (atomicAdd(&bcur[i], c) + i * BUKCAP - loc[i]) : 0;
    }
    __syncthreads();
#pragma unroll
    for (int q = 0; q < 8; ++q) {
        if (dreg[q] >= 0) {
            int s = sreg[q], d = dreg[q];
            int b = d >> 8;
            int slot = loc[b] + rreg[q];
            sp[slot]  = ((unsigned)(d & 255) << 17) | (unsigned)s;
            bid[slot] = (unsigned short)b;
        }
    }
    __syncthreads();
    for (int i = tid; i < tilecnt; i += 1024)
        pairs[cur[bid[i]] + i] = sp[i];
}

// ---------------- per-bucket counting sort + record-gather: emits rowcnt, adj, recS ----------------
__global__ __launch_bounds__(1024) void k_bsort(const int* __restrict__ bcur,
                                                unsigned* __restrict__ pairs,
                                                const unsigned* __restrict__ rec,
                                                unsigned* __restrict__ recS,
                                                int2* __restrict__ rowcnt) {
    __shared__ int srt[BUKCAP];     // 32KB sorted srcs
    __shared__ int hist[256], sc[256];
    int b = blockIdx.x;
    int cnt = bcur[b];
    if (cnt > BUKCAP) cnt = BUKCAP;
    int base = b * BUKCAP;
    int tid = threadIdx.x;
    if (tid < 256) hist[tid] = 0;
    __syncthreads();
    // pass 1: vectorized read (8 contiguous pairs/thread), rank-atomic, registers
    unsigned preg[8];
    int rreg[8];
    int i0 = tid * 8;
    if (i0 + 8 <= cnt) {
        const uint4 v0 = *(const uint4*)(pairs + base + i0);
        const uint4 v1 = *(const uint4*)(pairs + base + i0 + 4);
        preg[0] = v0.x; preg[1] = v0.y; preg[2] = v0.z; preg[3] = v0.w;
        preg[4] = v1.x; preg[5] = v1.y; preg[6] = v1.z; preg[7] = v1.w;
    } else {
#pragma unroll
        for (int j = 0; j < 8; ++j)
            preg[j] = (i0 + j < cnt) ? pairs[base + i0 + j] : 0xFFFFFFFFu;
    }
#pragma unroll
    for (int j = 0; j < 8; ++j)
        if (preg[j] != 0xFFFFFFFFu) rreg[j] = atomicAdd(&hist[preg[j] >> 17], 1);
    __syncthreads();
    // 256-bin exclusive scan on wave 0 (4 bins/lane)
    if (tid < 64) {
        int v0 = hist[4 * tid], v1 = hist[4 * tid + 1];
        int v2 = hist[4 * tid + 2], v3 = hist[4 * tid + 3];
        int s = v0 + v1 + v2 + v3;
#pragma unroll
        for (int o = 1; o < 64; o <<= 1) {
            int t = __shfl(s, (tid - o) & 63);
            if (tid >= o) s += t;
        }
        int excl = s - v0 - v1 - v2 - v3;
        sc[4 * tid]     = excl;
        sc[4 * tid + 1] = excl + v0;
        sc[4 * tid + 2] = excl + v0 + v1;
        sc[4 * tid + 3] = excl + v0 + v1 + v2;
    }
    __syncthreads();
    int nbase = b << 8;
    if (tid < 256 && nbase + tid < NN)
        rowcnt[nbase + tid] = make_int2(base + sc[tid], hist[tid]);
    // scatter into LDS (cheap), then flush contiguously: adj ints + gathered 16B records
#pragma unroll
    for (int j = 0; j < 8; ++j) {
        if (preg[j] != 0xFFFFFFFFu) {
            int ld = (int)(preg[j] >> 17);
            srt[sc[ld] + rreg[j]] = (int)(preg[j] & 0x1FFFF);
        }
    }
    __syncthreads();
    int* adj = (int*)pairs;   // aliases pairs; all pairs reads completed above
    for (int i = tid; i < cnt; i += 1024) {
        int s = srt[i];
        adj[base + i] = s;
        *(uint4*)(recS + (size_t)(base + i) * 4) = *(const uint4*)(rec + (size_t)s * 4);
    }
}

// ---------------- layer 1 generic fallback (deg>32): single pass, no max, streamed records ----------------
__device__ __forceinline__ void agg1_node_gen(int n, int lane, int off, int deg,
                                              const unsigned* __restrict__ recS,
                                              const float* __restrict__ sd1,
                                              const float* __restrict__ W1,
                                              const float* __restrict__ b1,
                                              const float* __restrict__ W2,
                                              float* __restrict__ h2) {
    float sdn = sd1[n];
    float dsum = 0.f, a0 = 0.f, a1 = 0.f, a2 = 0.f, a3 = 0.f, a4 = 0.f;
    for (int j0 = 0; j0 < deg; j0 += 64) {
        int j = j0 + lane;
        if (j < deg) {
            const uint4 v = *(const uint4*)(recS + (size_t)(off + j) * 4);
            float t = __uint_as_float(v.x) + sdn;
            float e = t > 0.f ? t : NEG * t;
            float w = __expf(e);
            dsum += w;
            a0 += w * uh(v.y); a1 += w * uh(v.y >> 16);
            a2 += w * uh(v.z); a3 += w * uh(v.z >> 16);
            a4 += w * uh(v.w);
        }
    }
#pragma unroll
    for (int o = 32; o; o >>= 1) {
        dsum += __shfl_xor(dsum, o);
        a0 += __shfl_xor(a0, o); a1 += __shfl_xor(a1, o); a2 += __shfl_xor(a2, o);
        a3 += __shfl_xor(a3, o); a4 += __shfl_xor(a4, o);
    }
    float inv = 1.0f / dsum;
    a0 *= inv; a1 *= inv; a2 *= inv; a3 *= inv; a4 *= inv;
    float of = b1[lane] + a0 * W1[lane] + a1 * W1[64 + lane] + a2 * W1[128 + lane]
             + a3 * W1[192 + lane] + a4 * W1[256 + lane];
    of = fmaxf(of, 0.f);
    float p2 = of * W2[lane];
#pragma unroll
    for (int o = 32; o; o >>= 1) p2 += __shfl_xor(p2, o);
    if (lane == 0) h2[n] = p2;
}

// ---------------- layer 1: lane=edge, 2 nodes per wave, coalesced record stream ----------------
__global__ __launch_bounds__(256) void k_agg1(const int* __restrict__ rowcnt,
                                              const unsigned* __restrict__ recS,
                                              const float* __restrict__ sd1,
                                              const float* __restrict__ W1,
                                              const float* __restrict__ b1,
                                              const float* __restrict__ W2,
                                              float* __restrict__ h2) {
    int wid  = threadIdx.x >> 6;
    int lane = threadIdx.x & 63;
    int n0 = (blockIdx.x * 4 + wid) * 2;
    if (n0 >= NN) return;
    const int4 rc = *(const int4*)(rowcnt + n0 * 2);
    int off0 = rc.x, d0 = rc.y, off1 = rc.z, d1 = rc.w;

    if (d0 <= 32 && d1 <= 32) {
        int half = lane >> 5, li = lane & 31;
        int n = n0 + half;
        int off = half ? off1 : off0;
        int deg = half ? d1 : d0;
        float sdn = sd1[n];
        const uint4 v = *(const uint4*)(recS + (size_t)(off + (li < deg ? li : 0)) * 4);
        float t = __uint_as_float(v.x) + sdn;
        float e = t > 0.f ? t : NEG * t;
        float p = (li < deg) ? __expf(e) : 0.f;
        float ds = p;
        float a0 = p * uh(v.y), a1 = p * uh(v.y >> 16);
        float a2 = p * uh(v.z), a3 = p * uh(v.z >> 16);
        float a4 = p * uh(v.w);
#pragma unroll
        for (int o = 1; o <= 16; o <<= 1) {
            ds += __shfl_xor(ds, o);
            a0 += __shfl_xor(a0, o); a1 += __shfl_xor(a1, o); a2 += __shfl_xor(a2, o);
            a3 += __shfl_xor(a3, o); a4 += __shfl_xor(a4, o);
        }
        float inv = 1.0f / ds;
        a0 *= inv; a1 *= inv; a2 *= inv; a3 *= inv; a4 *= inv;
        float o0 = b1[li] + a0 * W1[li] + a1 * W1[64 + li] + a2 * W1[128 + li]
                 + a3 * W1[192 + li] + a4 * W1[256 + li];
        float o1 = b1[li + 32] + a0 * W1[li + 32] + a1 * W1[96 + li] + a2 * W1[160 + li]
                 + a3 * W1[224 + li] + a4 * W1[288 + li];
        o0 = fmaxf(o0, 0.f);
        o1 = fmaxf(o1, 0.f);
        float p2 = o0 * W2[li] + o1 * W2[li + 32];
#pragma unroll
        for (int o = 1; o <= 16; o <<= 1) p2 += __shfl_xor(p2, o);
        if (li == 0) h2[n] = p2;
    } else {
        agg1_node_gen(n0,     lane, off0, d0, recS, sd1, W1, b1, W2, h2);
        agg1_node_gen(n0 + 1, lane, off1, d1, recS, sd1, W1, b1, W2, h2);
    }
}

// ---------------- layer 2: full-wave single-node fallback (no max, single pass) ----------------
__device__ __forceinline__ void agg2_node(int n, int lane, int off, int deg,
                                          const int* __restrict__ adj,
                                          const float* __restrict__ h2,
                                          float as2v, float ad2v, float b2v,
                                          float* __restrict__ out) {
    float sdn = h2[n] * ad2v;
    float dsum = 0.f, nsum = 0.f;
    for (int j0 = 0; j0 < deg; j0 += 64) {
        int j = j0 + lane;
        if (j < deg) {
            int s = adj[off + j];
            float hv = h2[s];
            float e = hv * as2v + sdn;
            e = e > 0.f ? e : NEG * e;
            float ex = __expf(e);
            dsum += ex;
            nsum += ex * hv;
        }
    }
#pragma unroll
    for (int o = 32; o; o >>= 1) { dsum += __shfl_xor(dsum, o); nsum += __shfl_xor(nsum, o); }
    if (lane == 0) out[n] = nsum / dsum + b2v;
}

// ---------------- layer 2: 4 nodes per wave, no max ----------------
__global__ __launch_bounds__(256) void k_agg2(const int* __restrict__ rowcnt,
                                              const int* __restrict__ adj,
                                              const float* __restrict__ h2,
                                              const float* __restrict__ as2,
                                              const float* __restrict__ ad2,
                                              const float* __restrict__ b2,
                                              float* __restrict__ out) {
    int wid  = threadIdx.x >> 6;
    int lane = threadIdx.x & 63;
    int n0 = (blockIdx.x * 4 + wid) * 4;
    if (n0 >= NN) return;
    float as2v = as2[0], ad2v = ad2[0], b2v = b2[0];
    const int4 rcA = *(const int4*)(rowcnt + n0 * 2);
    const int4 rcB = *(const int4*)(rowcnt + n0 * 2 + 4);
    int d0 = rcA.y, d1 = rcA.w, d2 = rcB.y, d3 = rcB.w;

    if (d0 <= 32 && d1 <= 32 && d2 <= 32 && d3 <= 32) {
        int half = lane >> 5, li = lane & 31;
        int nA = n0 + half, nB = n0 + 2 + half;
        int offA = half ? rcA.z : rcA.x;
        int offB = half ? rcB.z : rcB.x;
        int degA = half ? d1 : d0, degB = half ? d3 : d2;
        float sdA = h2[nA] * ad2v, sdB = h2[nB] * ad2v;
        float hvA = 0.f, hvB = 0.f, pA = 0.f, pB = 0.f;
        if (li < degA) {
            hvA = h2[adj[offA + li]];
            float t = hvA * as2v + sdA;
            pA = __expf(t > 0.f ? t : NEG * t);
        }
        if (li < degB) {
            hvB = h2[adj[offB + li]];
            float t = hvB * as2v + sdB;
            pB = __expf(t > 0.f ? t : NEG * t);
        }
        float dsA = pA, dsB = pB, nsA = pA * hvA, nsB = pB * hvB;
#pragma unroll
        for (int o = 1; o <= 16; o <<= 1) {
            dsA += __shfl_xor(dsA, o); nsA += __shfl_xor(nsA, o);
            dsB += __shfl_xor(dsB, o); nsB += __shfl_xor(nsB, o);
        }
        if (li == 0) {
            out[nA] = nsA / dsA + b2v;
            out[nB] = nsB / dsB + b2v;
        }
    } else {
        agg2_node(n0,     lane, rcA.x, d0, adj, h2, as2v, ad2v, b2v, out);
        agg2_node(n0 + 1, lane, rcA.z, d1, adj, h2, as2v, ad2v, b2v, out);
        agg2_node(n0 + 2, lane, rcB.x, d2, adj, h2, as2v, ad2v, b2v, out);
        agg2_node(n0 + 3, lane, rcB.z, d3, adj, h2, as2v, ad2v, b2v, out);
    }
}

extern "C" void kernel_launch(void* const* d_in, const int* in_sizes, int n_in,
                              void* d_out, int out_size, void* d_ws, size_t ws_size,
                              hipStream_t stream) {
    const float* x      = (const float*)d_in[0];
    const int*   ei     = (const int*)d_in[1];
    const float* W1     = (const float*)d_in[2];
    const float* a_src1 = (const float*)d_in[3];
    const float* a_dst1 = (const float*)d_in[4];
    const float* b1     = (const float*)d_in[5];
    const float* W2     = (const float*)d_in[6];
    const float* as2    = (const float*)d_in[7];
    const float* ad2    = (const float*)d_in[8];
    const float* b2     = (const float*)d_in[9];
    float* out = (float*)d_out;

    // workspace layout (all 4-byte elements)
    unsigned* rec = (unsigned*)d_ws;                    // N*4 words = 1.6MB
    float* sd1  = (float*)(rec + (size_t)NN * 4);       // N
    float* h2   = sd1 + NN;                             // N
    int2* rowcnt = (int2*)(h2 + NN);                    // N int2 (16B-aligned pairs)
    int* bcur   = (int*)(rowcnt + NN);                  // 1024
    unsigned* pairs = (unsigned*)(bcur + 1024);         // NBUK*BUKCAP = 12.8MB (reused as adj)
    int* adj    = (int*)pairs;
    unsigned* recS = pairs + (size_t)NBUK * BUKCAP;     // NBUK*BUKCAP*4 words = 51.2MB

    const int NPAIR = (NN / 2 + 3) / 4;                 // 12500 blocks, 2 nodes/wave
    const int NQUAD = (NN + 15) / 16;                   // 6250 blocks, 4 nodes/wave

    hipMemsetAsync(bcur, 0, 1024 * sizeof(int), stream);
    k_front<<<NSCT + NPROJB, 1024, 0, stream>>>(x, W1, a_src1, a_dst1, ei,
                                                rec, sd1, bcur, pairs);
    k_bsort<<<NBUK, 1024, 0, stream>>>(bcur, pairs, rec, recS, rowcnt);
    k_agg1<<<NPAIR, 256, 0, stream>>>((const int*)rowcnt, recS, sd1, W1, b1, W2, h2);
    k_agg2<<<NQUAD, 256, 0, stream>>>((const int*)rowcnt, adj, h2, as2, ad2, b2, out);
}

// Round 23
// 70.571 us; speedup vs baseline: 1.0994x; 1.0994x over previous
//
#include <hip/hip_runtime.h>
#include <hip/hip_bf16.h>
#include <hip/hip_fp16.h>

#define NN 100000
#define EE 1600000
#define ET (EE + NN)            // edges incl. self loops
#define HID 64
#define NEG 0.2f
#define NBUK 391                // ceil(NN/256) buckets of 256 dst nodes
#define SCT_TILE 8192           // edges per block in scatter phase (1024 thr x 8)
#define BUKCAP 8192             // padded per-bucket capacity (mean 4352, sigma~66)

__device__ __forceinline__ float uh(unsigned u) {
    __half_raw r; r.x = (unsigned short)(u & 0xFFFF);
    return __half2float(__half(r));
}
__device__ __forceinline__ unsigned f2h(float f) {
    __half h = __float2half_rn(f);
    __half_raw r = *reinterpret_cast<__half_raw*>(&h);
    return (unsigned)r.x;
}

#define NSCT ((ET + SCT_TILE - 1) / SCT_TILE)   // 208 scatter-role blocks
#define NPROJB ((NN + 31) / 32)                 // 3125 proj-role blocks (32 nodes each)

// ---------------- merged front kernel: scatter role (blocks < NSCT) + proj role ----------------
__global__ __launch_bounds__(1024) void k_front(const float* __restrict__ x,
                                                const float* __restrict__ W1,
                                                const float* __restrict__ a_src1,
                                                const float* __restrict__ a_dst1,
                                                const int* __restrict__ ei,
                                                unsigned* __restrict__ rec,
                                                float* __restrict__ sd1,
                                                int* __restrict__ bcur,
                                                unsigned* __restrict__ pairs) {
    __shared__ unsigned sp[SCT_TILE];
    __shared__ unsigned short bid[SCT_TILE];
    __shared__ int cnt_[NBUK], loc[NBUK], cur[NBUK];
    __shared__ int wsum[16];
    int tid = threadIdx.x;

    if (blockIdx.x >= NSCT) {
        // ---- proj role: 16 waves x 2 nodes = 32 nodes per block ----
        int p = blockIdx.x - NSCT;
        int wid  = tid >> 6;
        int half = (tid >> 5) & 1, li = tid & 31;
        int n = p * 32 + wid * 2 + half;
        if (n >= NN) return;
        float xv[5];
        float h0 = 0.f, h1 = 0.f;
#pragma unroll
        for (int k = 0; k < 5; ++k) {
            xv[k] = x[n * 5 + k];
            h0 += xv[k] * W1[k * HID + li];
            h1 += xv[k] * W1[k * HID + li + 32];
        }
        float a = h0 * a_src1[li] + h1 * a_src1[li + 32];
        float b = h0 * a_dst1[li] + h1 * a_dst1[li + 32];
#pragma unroll
        for (int o = 1; o <= 16; o <<= 1) { a += __shfl_xor(a, o); b += __shfl_xor(b, o); }
        if (li == 0) {
            sd1[n] = b;
            uint4 rv;
            rv.x = __float_as_uint(a);
            rv.y = f2h(xv[0]) | (f2h(xv[1]) << 16);
            rv.z = f2h(xv[2]) | (f2h(xv[3]) << 16);
            rv.w = f2h(xv[4]);
            *(uint4*)(rec + (size_t)n * 4) = rv;
        }
        return;
    }

    // ---- scatter role ----
    int wid = tid >> 6, lane = tid & 63;
    int base = blockIdx.x * SCT_TILE;
    int tilecnt = ET - base; if (tilecnt > SCT_TILE) tilecnt = SCT_TILE;

    for (int i = tid; i < NBUK; i += 1024) cnt_[i] = 0;
    __syncthreads();
    int sreg[8], dreg[8], rreg[8];
#pragma unroll
    for (int it = 0; it < 2; ++it) {
        int i = base + (it * 1024 + tid) * 4;
        if (i + 3 < EE) {
            const int4 sv = *(const int4*)(ei + i);
            const int4 dv = *(const int4*)(ei + EE + i);
            sreg[it*4+0] = sv.x; sreg[it*4+1] = sv.y; sreg[it*4+2] = sv.z; sreg[it*4+3] = sv.w;
            dreg[it*4+0] = dv.x; dreg[it*4+1] = dv.y; dreg[it*4+2] = dv.z; dreg[it*4+3] = dv.w;
        } else {
#pragma unroll
            for (int k = 0; k < 4; ++k) {
                int idx = i + k;
                if (idx < EE)      { sreg[it*4+k] = ei[idx];  dreg[it*4+k] = ei[EE + idx]; }
                else if (idx < ET) { sreg[it*4+k] = idx - EE; dreg[it*4+k] = idx - EE; }
                else               { dreg[it*4+k] = -1; }
            }
        }
#pragma unroll
        for (int k = 0; k < 4; ++k)
            if (dreg[it*4+k] >= 0) rreg[it*4+k] = atomicAdd(&cnt_[dreg[it*4+k] >> 8], 1);
    }
    __syncthreads();
    int b0 = tid * 4;
    int s0 = 0;
    if (b0 < NBUK)
        for (int k = 0; k < 4 && b0 + k < NBUK; ++k) s0 += cnt_[b0 + k];
    int incl = s0;
#pragma unroll
    for (int o = 1; o < 64; o <<= 1) {
        int t = __shfl(incl, (lane - o) & 63);
        if (lane >= o) incl += t;
    }
    if (lane == 63) wsum[wid] = incl;
    __syncthreads();
    int wpref = 0;
    for (int w = 0; w < wid; ++w) wpref += wsum[w];
    if (b0 < NBUK) {
        int run = wpref + incl - s0;
        for (int k = 0; k < 4 && b0 + k < NBUK; ++k) {
            loc[b0 + k] = run;
            run += cnt_[b0 + k];
        }
    }
    __syncthreads();
    for (int i = tid; i < NBUK; i += 1024) {
        int c = cnt_[i];
        cur[i] = c ? (atomicAdd(&bcur[i], c) + i * BUKCAP - loc[i]) : 0;
    }
    __syncthreads();
#pragma unroll
    for (int q = 0; q < 8; ++q) {
        if (dreg[q] >= 0) {
            int s = sreg[q], d = dreg[q];
            int b = d >> 8;
            int slot = loc[b] + rreg[q];
            sp[slot]  = ((unsigned)(d & 255) << 17) | (unsigned)s;
            bid[slot] = (unsigned short)b;
        }
    }
    __syncthreads();
    for (int i = tid; i < tilecnt; i += 1024)
        pairs[cur[bid[i]] + i] = sp[i];
}

// ---------------- per-bucket counting sort: LDS-staged sort, CONTIGUOUS adj flush ----------------
__global__ __launch_bounds__(1024) void k_bsort(const int* __restrict__ bcur,
                                                unsigned* __restrict__ pairs,
                                                int2* __restrict__ rowcnt) {
    __shared__ int srt[BUKCAP];     // 32KB sorted srcs
    __shared__ int hist[256], sc[256];
    int b = blockIdx.x;
    int cnt = bcur[b];
    if (cnt > BUKCAP) cnt = BUKCAP;
    int base = b * BUKCAP;
    int tid = threadIdx.x;
    if (tid < 256) hist[tid] = 0;
    __syncthreads();
    // pass 1: vectorized read (8 contiguous pairs/thread), rank-atomic, registers
    unsigned preg[8];
    int rreg[8];
    int i0 = tid * 8;
    if (i0 + 8 <= cnt) {
        const uint4 v0 = *(const uint4*)(pairs + base + i0);
        const uint4 v1 = *(const uint4*)(pairs + base + i0 + 4);
        preg[0] = v0.x; preg[1] = v0.y; preg[2] = v0.z; preg[3] = v0.w;
        preg[4] = v1.x; preg[5] = v1.y; preg[6] = v1.z; preg[7] = v1.w;
    } else {
#pragma unroll
        for (int j = 0; j < 8; ++j)
            preg[j] = (i0 + j < cnt) ? pairs[base + i0 + j] : 0xFFFFFFFFu;
    }
#pragma unroll
    for (int j = 0; j < 8; ++j)
        if (preg[j] != 0xFFFFFFFFu) rreg[j] = atomicAdd(&hist[preg[j] >> 17], 1);
    __syncthreads();
    // 256-bin exclusive scan on wave 0 (4 bins/lane)
    if (tid < 64) {
        int v0 = hist[4 * tid], v1 = hist[4 * tid + 1];
        int v2 = hist[4 * tid + 2], v3 = hist[4 * tid + 3];
        int s = v0 + v1 + v2 + v3;
#pragma unroll
        for (int o = 1; o < 64; o <<= 1) {
            int t = __shfl(s, (tid - o) & 63);
            if (tid >= o) s += t;
        }
        int excl = s - v0 - v1 - v2 - v3;
        sc[4 * tid]     = excl;
        sc[4 * tid + 1] = excl + v0;
        sc[4 * tid + 2] = excl + v0 + v1;
        sc[4 * tid + 3] = excl + v0 + v1 + v2;
    }
    __syncthreads();
    int nbase = b << 8;
    if (tid < 256 && nbase + tid < NN)
        rowcnt[nbase + tid] = make_int2(base + sc[tid], hist[tid]);
    // scatter into LDS (cheap: <=2-way bank aliasing), then flush contiguously
#pragma unroll
    for (int j = 0; j < 8; ++j) {
        if (preg[j] != 0xFFFFFFFFu) {
            int ld = (int)(preg[j] >> 17);
            srt[sc[ld] + rreg[j]] = (int)(preg[j] & 0x1FFFF);
        }
    }
    __syncthreads();
    int* adj = (int*)pairs;   // aliases pairs; all pairs reads completed above
    for (int i = tid; i < cnt; i += 1024)
        adj[base + i] = srt[i];
}

// ---------------- layer 1 generic fallback (deg>32): single pass, no max, 16B record ----------------
__device__ __forceinline__ void agg1_node_gen(int n, int lane, int off, int deg,
                                              const int* __restrict__ adj,
                                              const unsigned* __restrict__ rec,
                                              const float* __restrict__ sd1,
                                              const float* __restrict__ W1,
                                              const float* __restrict__ b1,
                                              const float* __restrict__ W2,
                                              float* __restrict__ h2) {
    float sdn = sd1[n];
    float dsum = 0.f, a0 = 0.f, a1 = 0.f, a2 = 0.f, a3 = 0.f, a4 = 0.f;
    for (int j0 = 0; j0 < deg; j0 += 64) {
        int j = j0 + lane;
        if (j < deg) {
            int s = adj[off + j];
            const uint4 v = *(const uint4*)(rec + (size_t)s * 4);
            float t = __uint_as_float(v.x) + sdn;
            float e = t > 0.f ? t : NEG * t;
            float w = __expf(e);
            dsum += w;
            a0 += w * uh(v.y); a1 += w * uh(v.y >> 16);
            a2 += w * uh(v.z); a3 += w * uh(v.z >> 16);
            a4 += w * uh(v.w);
        }
    }
#pragma unroll
    for (int o = 32; o; o >>= 1) {
        dsum += __shfl_xor(dsum, o);
        a0 += __shfl_xor(a0, o); a1 += __shfl_xor(a1, o); a2 += __shfl_xor(a2, o);
        a3 += __shfl_xor(a3, o); a4 += __shfl_xor(a4, o);
    }
    float inv = 1.0f / dsum;
    a0 *= inv; a1 *= inv; a2 *= inv; a3 *= inv; a4 *= inv;
    float of = b1[lane] + a0 * W1[lane] + a1 * W1[64 + lane] + a2 * W1[128 + lane]
             + a3 * W1[192 + lane] + a4 * W1[256 + lane];
    of = fmaxf(of, 0.f);
    float p2 = of * W2[lane];
#pragma unroll
    for (int o = 32; o; o >>= 1) p2 += __shfl_xor(p2, o);
    if (lane == 0) h2[n] = p2;
}

// ---------------- layer 1: lane=edge, 2 nodes per wave, no max, ONE 16B gather/edge ----------------
__global__ __launch_bounds__(256) void k_agg1(const int* __restrict__ rowcnt,
                                              const int* __restrict__ adj,
                                              const unsigned* __restrict__ rec,
                                              const float* __restrict__ sd1,
                                              const float* __restrict__ W1,
                                              const float* __restrict__ b1,
                                              const float* __restrict__ W2,
                                              float* __restrict__ h2) {
    int wid  = threadIdx.x >> 6;
    int lane = threadIdx.x & 63;
    int n0 = (blockIdx.x * 4 + wid) * 2;
    if (n0 >= NN) return;
    const int4 rc = *(const int4*)(rowcnt + n0 * 2);
    int off0 = rc.x, d0 = rc.y, off1 = rc.z, d1 = rc.w;

    if (d0 <= 32 && d1 <= 32) {
        int half = lane >> 5, li = lane & 31;
        int n = n0 + half;
        int off = half ? off1 : off0;
        int deg = half ? d1 : d0;
        float sdn = sd1[n];
        int s = adj[off + (li < deg ? li : 0)];
        const uint4 v = *(const uint4*)(rec + (size_t)s * 4);
        float t = __uint_as_float(v.x) + sdn;
        float e = t > 0.f ? t : NEG * t;
        float p = (li < deg) ? __expf(e) : 0.f;
        float ds = p;
        float a0 = p * uh(v.y), a1 = p * uh(v.y >> 16);
        float a2 = p * uh(v.z), a3 = p * uh(v.z >> 16);
        float a4 = p * uh(v.w);
#pragma unroll
        for (int o = 1; o <= 16; o <<= 1) {
            ds += __shfl_xor(ds, o);
            a0 += __shfl_xor(a0, o); a1 += __shfl_xor(a1, o); a2 += __shfl_xor(a2, o);
            a3 += __shfl_xor(a3, o); a4 += __shfl_xor(a4, o);
        }
        float inv = 1.0f / ds;
        a0 *= inv; a1 *= inv; a2 *= inv; a3 *= inv; a4 *= inv;
        float o0 = b1[li] + a0 * W1[li] + a1 * W1[64 + li] + a2 * W1[128 + li]
                 + a3 * W1[192 + li] + a4 * W1[256 + li];
        float o1 = b1[li + 32] + a0 * W1[li + 32] + a1 * W1[96 + li] + a2 * W1[160 + li]
                 + a3 * W1[224 + li] + a4 * W1[288 + li];
        o0 = fmaxf(o0, 0.f);
        o1 = fmaxf(o1, 0.f);
        float p2 = o0 * W2[li] + o1 * W2[li + 32];
#pragma unroll
        for (int o = 1; o <= 16; o <<= 1) p2 += __shfl_xor(p2, o);
        if (li == 0) h2[n] = p2;
    } else {
        agg1_node_gen(n0,     lane, off0, d0, adj, rec, sd1, W1, b1, W2, h2);
        agg1_node_gen(n0 + 1, lane, off1, d1, adj, rec, sd1, W1, b1, W2, h2);
    }
}

// ---------------- layer 2: full-wave single-node fallback (no max, single pass) ----------------
__device__ __forceinline__ void agg2_node(int n, int lane, int off, int deg,
                                          const int* __restrict__ adj,
                                          const float* __restrict__ h2,
                                          float as2v, float ad2v, float b2v,
                                          float* __restrict__ out) {
    float sdn = h2[n] * ad2v;
    float dsum = 0.f, nsum = 0.f;
    for (int j0 = 0; j0 < deg; j0 += 64) {
        int j = j0 + lane;
        if (j < deg) {
            int s = adj[off + j];
            float hv = h2[s];
            float e = hv * as2v + sdn;
            e = e > 0.f ? e : NEG * e;
            float ex = __expf(e);
            dsum += ex;
            nsum += ex * hv;
        }
    }
#pragma unroll
    for (int o = 32; o; o >>= 1) { dsum += __shfl_xor(dsum, o); nsum += __shfl_xor(nsum, o); }
    if (lane == 0) out[n] = nsum / dsum + b2v;
}

// ---------------- layer 2: 4 nodes per wave, no max ----------------
__global__ __launch_bounds__(256) void k_agg2(const int* __restrict__ rowcnt,
                                              const int* __restrict__ adj,
                                              const float* __restrict__ h2,
                                              const float* __restrict__ as2,
                                              const float* __restrict__ ad2,
                                              const float* __restrict__ b2,
                                              float* __restrict__ out) {
    int wid  = threadIdx.x >> 6;
    int lane = threadIdx.x & 63;
    int n0 = (blockIdx.x * 4 + wid) * 4;
    if (n0 >= NN) return;
    float as2v = as2[0], ad2v = ad2[0], b2v = b2[0];
    const int4 rcA = *(const int4*)(rowcnt + n0 * 2);
    const int4 rcB = *(const int4*)(rowcnt + n0 * 2 + 4);
    int d0 = rcA.y, d1 = rcA.w, d2 = rcB.y, d3 = rcB.w;

    if (d0 <= 32 && d1 <= 32 && d2 <= 32 && d3 <= 32) {
        int half = lane >> 5, li = lane & 31;
        int nA = n0 + half, nB = n0 + 2 + half;
        int offA = half ? rcA.z : rcA.x;
        int offB = half ? rcB.z : rcB.x;
        int degA = half ? d1 : d0, degB = half ? d3 : d2;
        float sdA = h2[nA] * ad2v, sdB = h2[nB] * ad2v;
        float hvA = 0.f, hvB = 0.f, pA = 0.f, pB = 0.f;
        if (li < degA) {
            hvA = h2[adj[offA + li]];
            float t = hvA * as2v + sdA;
            pA = __expf(t > 0.f ? t : NEG * t);
        }
        if (li < degB) {
            hvB = h2[adj[offB + li]];
            float t = hvB * as2v + sdB;
            pB = __expf(t > 0.f ? t : NEG * t);
        }
        float dsA = pA, dsB = pB, nsA = pA * hvA, nsB = pB * hvB;
#pragma unroll
        for (int o = 1; o <= 16; o <<= 1) {
            dsA += __shfl_xor(dsA, o); nsA += __shfl_xor(nsA, o);
            dsB += __shfl_xor(dsB, o); nsB += __shfl_xor(nsB, o);
        }
        if (li == 0) {
            out[nA] = nsA / dsA + b2v;
            out[nB] = nsB / dsB + b2v;
        }
    } else {
        agg2_node(n0,     lane, rcA.x, d0, adj, h2, as2v, ad2v, b2v, out);
        agg2_node(n0 + 1, lane, rcA.z, d1, adj, h2, as2v, ad2v, b2v, out);
        agg2_node(n0 + 2, lane, rcB.x, d2, adj, h2, as2v, ad2v, b2v, out);
        agg2_node(n0 + 3, lane, rcB.z, d3, adj, h2, as2v, ad2v, b2v, out);
    }
}

extern "C" void kernel_launch(void* const* d_in, const int* in_sizes, int n_in,
                              void* d_out, int out_size, void* d_ws, size_t ws_size,
                              hipStream_t stream) {
    const float* x      = (const float*)d_in[0];
    const int*   ei     = (const int*)d_in[1];
    const float* W1     = (const float*)d_in[2];
    const float* a_src1 = (const float*)d_in[3];
    const float* a_dst1 = (const float*)d_in[4];
    const float* b1     = (const float*)d_in[5];
    const float* W2     = (const float*)d_in[6];
    const float* as2    = (const float*)d_in[7];
    const float* ad2    = (const float*)d_in[8];
    const float* b2     = (const float*)d_in[9];
    float* out = (float*)d_out;

    // workspace layout (all 4-byte elements)
    unsigned* rec = (unsigned*)d_ws;                    // N*4 words = 1.6MB
    float* sd1  = (float*)(rec + (size_t)NN * 4);       // N
    float* h2   = sd1 + NN;                             // N
    int2* rowcnt = (int2*)(h2 + NN);                    // N int2 (16B-aligned pairs)
    int* bcur   = (int*)(rowcnt + NN);                  // 1024
    unsigned* pairs = (unsigned*)(bcur + 1024);         // NBUK*BUKCAP = 12.8MB (reused as adj)
    int* adj    = (int*)pairs;

    const int NPAIR = (NN / 2 + 3) / 4;                 // 12500 blocks, 2 nodes/wave
    const int NQUAD = (NN + 15) / 16;                   // 6250 blocks, 4 nodes/wave

    hipMemsetAsync(bcur, 0, 1024 * sizeof(int), stream);
    k_front<<<NSCT + NPROJB, 1024, 0, stream>>>(x, W1, a_src1, a_dst1, ei,
                                                rec, sd1, bcur, pairs);
    k_bsort<<<NBUK, 1024, 0, stream>>>(bcur, pairs, rowcnt);
    k_agg1<<<NPAIR, 256, 0, stream>>>((const int*)rowcnt, adj, rec, sd1, W1, b1, W2, h2);
    k_agg2<<<NQUAD, 256, 0, stream>>>((const int*)rowcnt, adj, h2, as2, ad2, b2, out);
}

// Round 25
// 70.563 us; speedup vs baseline: 1.0995x; 1.0001x over previous
//
#include <hip/hip_runtime.h>
#include <hip/hip_bf16.h>
#include <hip/hip_fp16.h>
#include <hip/hip_cooperative_groups.h>

namespace cg = cooperative_groups;

#define NN 100000
#define EE 1600000
#define ET (EE + NN)            // edges incl. self loops
#define HID 64
#define NEG 0.2f
#define NBUK 391                // ceil(NN/256) buckets of 256 dst nodes
#define SCT_TILE 8192           // edges per scatter tile (1024 thr x 8)
#define BUKCAP 8192             // padded per-bucket capacity (mean 4352, sigma~66)
#define TPB 1024
#define NSCT ((ET + SCT_TILE - 1) / SCT_TILE)   // 208 scatter tiles
#define NPROJQ ((NN + 31) / 32)                 // 3125 proj quanta (32 nodes)
#define NAGG1Q ((NN + 31) / 32)                 // 3125 agg1 quanta (32 nodes)
#define NAGG2Q ((NN + 63) / 64)                 // 1563 agg2 quanta (64 nodes)

__device__ __forceinline__ float uh(unsigned u) {
    __half_raw r; r.x = (unsigned short)(u & 0xFFFF);
    return __half2float(__half(r));
}
__device__ __forceinline__ unsigned f2h(float f) {
    __half h = __float2half_rn(f);
    __half_raw r = *reinterpret_cast<__half_raw*>(&h);
    return (unsigned)r.x;
}

// ==================== device phase bodies (shared by mega & fallback) ====================

// scatter tile body: 1024 threads, 8 edges/thread (R21-proven)
template <typename SC>
__device__ __forceinline__ void scatter_tile(SC& sc, int q, int tid, int wid, int lane,
                                             const int* __restrict__ ei,
                                             int* __restrict__ bcur,
                                             unsigned* __restrict__ pairs) {
    int base = q * SCT_TILE;
    int tilecnt = ET - base; if (tilecnt > SCT_TILE) tilecnt = SCT_TILE;
    for (int i = tid; i < NBUK; i += TPB) sc.cnt_[i] = 0;
    __syncthreads();
    int sreg[8], dreg[8], rreg[8];
#pragma unroll
    for (int it = 0; it < 2; ++it) {
        int i = base + (it * TPB + tid) * 4;
        if (i + 3 < EE) {
            const int4 sv = *(const int4*)(ei + i);
            const int4 dv = *(const int4*)(ei + EE + i);
            sreg[it*4+0] = sv.x; sreg[it*4+1] = sv.y; sreg[it*4+2] = sv.z; sreg[it*4+3] = sv.w;
            dreg[it*4+0] = dv.x; dreg[it*4+1] = dv.y; dreg[it*4+2] = dv.z; dreg[it*4+3] = dv.w;
        } else {
#pragma unroll
            for (int k = 0; k < 4; ++k) {
                int idx = i + k;
                if (idx < EE)      { sreg[it*4+k] = ei[idx];  dreg[it*4+k] = ei[EE + idx]; }
                else if (idx < ET) { sreg[it*4+k] = idx - EE; dreg[it*4+k] = idx - EE; }
                else               { dreg[it*4+k] = -1; }
            }
        }
#pragma unroll
        for (int k = 0; k < 4; ++k)
            if (dreg[it*4+k] >= 0) rreg[it*4+k] = atomicAdd(&sc.cnt_[dreg[it*4+k] >> 8], 1);
    }
    __syncthreads();
    int b0 = tid * 4;
    int s0 = 0;
    if (b0 < NBUK)
        for (int k = 0; k < 4 && b0 + k < NBUK; ++k) s0 += sc.cnt_[b0 + k];
    int incl = s0;
#pragma unroll
    for (int o = 1; o < 64; o <<= 1) {
        int t = __shfl(incl, (lane - o) & 63);
        if (lane >= o) incl += t;
    }
    if (lane == 63) sc.wsum[wid] = incl;
    __syncthreads();
    int wpref = 0;
    for (int w = 0; w < wid; ++w) wpref += sc.wsum[w];
    if (b0 < NBUK) {
        int run = wpref + incl - s0;
        for (int k = 0; k < 4 && b0 + k < NBUK; ++k) {
            sc.loc[b0 + k] = run;
            run += sc.cnt_[b0 + k];
        }
    }
    __syncthreads();
    for (int i = tid; i < NBUK; i += TPB) {
        int c = sc.cnt_[i];
        sc.cur[i] = c ? (atomicAdd(&bcur[i], c) + i * BUKCAP - sc.loc[i]) : 0;
    }
    __syncthreads();
#pragma unroll
    for (int p = 0; p < 8; ++p) {
        if (dreg[p] >= 0) {
            int s = sreg[p], d = dreg[p];
            int b = d >> 8;
            int slot = sc.loc[b] + rreg[p];
            sc.sp[slot]  = ((unsigned)(d & 255) << 17) | (unsigned)s;
            sc.bid[slot] = (unsigned short)b;
        }
    }
    __syncthreads();
    for (int i = tid; i < tilecnt; i += TPB)
        pairs[sc.cur[sc.bid[i]] + i] = sc.sp[i];
    __syncthreads();
}

// proj quantum body: 16 waves x 2 nodes = 32 nodes (R21-proven)
__device__ __forceinline__ void proj_quantum(int p, int tid, int wid,
                                             const float* __restrict__ x,
                                             const float* __restrict__ W1,
                                             const float* __restrict__ a_src1,
                                             const float* __restrict__ a_dst1,
                                             unsigned* __restrict__ rec,
                                             float* __restrict__ sd1) {
    int half = (tid >> 5) & 1, li = tid & 31;
    int n = p * 32 + wid * 2 + half;
    if (n >= NN) return;
    float xv[5];
    float h0 = 0.f, h1 = 0.f;
#pragma unroll
    for (int k = 0; k < 5; ++k) {
        xv[k] = x[n * 5 + k];
        h0 += xv[k] * W1[k * HID + li];
        h1 += xv[k] * W1[k * HID + li + 32];
    }
    float a = h0 * a_src1[li] + h1 * a_src1[li + 32];
    float b = h0 * a_dst1[li] + h1 * a_dst1[li + 32];
#pragma unroll
    for (int o = 1; o <= 16; o <<= 1) { a += __shfl_xor(a, o); b += __shfl_xor(b, o); }
    if (li == 0) {
        sd1[n] = b;
        uint4 rv;
        rv.x = __float_as_uint(a);
        rv.y = f2h(xv[0]) | (f2h(xv[1]) << 16);
        rv.z = f2h(xv[2]) | (f2h(xv[3]) << 16);
        rv.w = f2h(xv[4]);
        *(uint4*)(rec + (size_t)n * 4) = rv;
    }
}

// bsort bucket body: 1024 threads, LDS-staged sort + contiguous flush (R21-proven)
template <typename BS>
__device__ __forceinline__ void bsort_bucket(BS& bs, int b, int tid,
                                             const int* __restrict__ bcur,
                                             unsigned* __restrict__ pairs,
                                             int2* __restrict__ rowcnt) {
    int cnt = bcur[b];
    if (cnt > BUKCAP) cnt = BUKCAP;
    int base = b * BUKCAP;
    if (tid < 256) bs.hist[tid] = 0;
    __syncthreads();
    unsigned preg[8];
    int rreg[8];
    int i0 = tid * 8;
    if (i0 + 8 <= cnt) {
        const uint4 v0 = *(const uint4*)(pairs + base + i0);
        const uint4 v1 = *(const uint4*)(pairs + base + i0 + 4);
        preg[0] = v0.x; preg[1] = v0.y; preg[2] = v0.z; preg[3] = v0.w;
        preg[4] = v1.x; preg[5] = v1.y; preg[6] = v1.z; preg[7] = v1.w;
    } else {
#pragma unroll
        for (int j = 0; j < 8; ++j)
            preg[j] = (i0 + j < cnt) ? pairs[base + i0 + j] : 0xFFFFFFFFu;
    }
#pragma unroll
    for (int j = 0; j < 8; ++j)
        if (preg[j] != 0xFFFFFFFFu) rreg[j] = atomicAdd(&bs.hist[preg[j] >> 17], 1);
    __syncthreads();
    if (tid < 64) {
        int v0 = bs.hist[4 * tid], v1 = bs.hist[4 * tid + 1];
        int v2 = bs.hist[4 * tid + 2], v3 = bs.hist[4 * tid + 3];
        int s = v0 + v1 + v2 + v3;
#pragma unroll
        for (int o = 1; o < 64; o <<= 1) {
            int t = __shfl(s, (tid - o) & 63);
            if (tid >= o) s += t;
        }
        int excl = s - v0 - v1 - v2 - v3;
        bs.scn[4 * tid]     = excl;
        bs.scn[4 * tid + 1] = excl + v0;
        bs.scn[4 * tid + 2] = excl + v0 + v1;
        bs.scn[4 * tid + 3] = excl + v0 + v1 + v2;
    }
    __syncthreads();
    int nbase = b << 8;
    if (tid < 256 && nbase + tid < NN)
        rowcnt[nbase + tid] = make_int2(base + bs.scn[tid], bs.hist[tid]);
#pragma unroll
    for (int j = 0; j < 8; ++j) {
        if (preg[j] != 0xFFFFFFFFu) {
            int ld = (int)(preg[j] >> 17);
            bs.srt[bs.scn[ld] + rreg[j]] = (int)(preg[j] & 0x1FFFF);
        }
    }
    __syncthreads();
    int* adj = (int*)pairs;   // aliases pairs; all pairs reads completed above
    for (int i = tid; i < cnt; i += TPB)
        adj[base + i] = bs.srt[i];
    __syncthreads();
}

// agg1 node-pair body (one wave), R21-proven
__device__ __forceinline__ void agg1_pair(int n0, int lane, const int4 rc,
                                          const int* __restrict__ adj,
                                          const unsigned* __restrict__ rec,
                                          const float* __restrict__ sd1,
                                          const float* __restrict__ W1,
                                          const float* __restrict__ b1,
                                          const float* __restrict__ W2,
                                          float* __restrict__ h2) {
    int off0 = rc.x, d0 = rc.y, off1 = rc.z, d1 = rc.w;
    if (d0 <= 32 && d1 <= 32) {
        int half = lane >> 5, li = lane & 31;
        int n = n0 + half;
        int off = half ? off1 : off0;
        int deg = half ? d1 : d0;
        float sdn = sd1[n];
        int s = adj[off + (li < deg ? li : 0)];
        const uint4 v = *(const uint4*)(rec + (size_t)s * 4);
        float t = __uint_as_float(v.x) + sdn;
        float e = t > 0.f ? t : NEG * t;
        float p = (li < deg) ? __expf(e) : 0.f;
        float ds = p;
        float a0 = p * uh(v.y), a1 = p * uh(v.y >> 16);
        float a2 = p * uh(v.z), a3 = p * uh(v.z >> 16);
        float a4 = p * uh(v.w);
#pragma unroll
        for (int o = 1; o <= 16; o <<= 1) {
            ds += __shfl_xor(ds, o);
            a0 += __shfl_xor(a0, o); a1 += __shfl_xor(a1, o); a2 += __shfl_xor(a2, o);
            a3 += __shfl_xor(a3, o); a4 += __shfl_xor(a4, o);
        }
        float inv = 1.0f / ds;
        a0 *= inv; a1 *= inv; a2 *= inv; a3 *= inv; a4 *= inv;
        float o0 = b1[li] + a0 * W1[li] + a1 * W1[64 + li] + a2 * W1[128 + li]
                 + a3 * W1[192 + li] + a4 * W1[256 + li];
        float o1 = b1[li + 32] + a0 * W1[li + 32] + a1 * W1[96 + li] + a2 * W1[160 + li]
                 + a3 * W1[224 + li] + a4 * W1[288 + li];
        o0 = fmaxf(o0, 0.f);
        o1 = fmaxf(o1, 0.f);
        float p2 = o0 * W2[li] + o1 * W2[li + 32];
#pragma unroll
        for (int o = 1; o <= 16; o <<= 1) p2 += __shfl_xor(p2, o);
        if (li == 0) h2[n] = p2;
    } else {
        for (int w = 0; w < 2; ++w) {
            int n = n0 + w;
            int off = w ? rc.z : rc.x;
            int deg = w ? rc.w : rc.y;
            float sdn = sd1[n];
            float dsum = 0.f, a0 = 0.f, a1 = 0.f, a2 = 0.f, a3 = 0.f, a4 = 0.f;
            for (int j0 = 0; j0 < deg; j0 += 64) {
                int j = j0 + lane;
                if (j < deg) {
                    int s = adj[off + j];
                    const uint4 v = *(const uint4*)(rec + (size_t)s * 4);
                    float t = __uint_as_float(v.x) + sdn;
                    float e = t > 0.f ? t : NEG * t;
                    float ww = __expf(e);
                    dsum += ww;
                    a0 += ww * uh(v.y); a1 += ww * uh(v.y >> 16);
                    a2 += ww * uh(v.z); a3 += ww * uh(v.z >> 16);
                    a4 += ww * uh(v.w);
                }
            }
#pragma unroll
            for (int o = 32; o; o >>= 1) {
                dsum += __shfl_xor(dsum, o);
                a0 += __shfl_xor(a0, o); a1 += __shfl_xor(a1, o); a2 += __shfl_xor(a2, o);
                a3 += __shfl_xor(a3, o); a4 += __shfl_xor(a4, o);
            }
            float inv = 1.0f / dsum;
            a0 *= inv; a1 *= inv; a2 *= inv; a3 *= inv; a4 *= inv;
            float of = b1[lane] + a0 * W1[lane] + a1 * W1[64 + lane] + a2 * W1[128 + lane]
                     + a3 * W1[192 + lane] + a4 * W1[256 + lane];
            of = fmaxf(of, 0.f);
            float p2 = of * W2[lane];
#pragma unroll
            for (int o = 32; o; o >>= 1) p2 += __shfl_xor(p2, o);
            if (lane == 0) h2[n] = p2;
        }
    }
}

// agg2 node-quad body (one wave), R21-proven
__device__ __forceinline__ void agg2_quad(int n0, int lane, const int4 rcA, const int4 rcB,
                                          const int* __restrict__ adj,
                                          const float* __restrict__ h2,
                                          float as2v, float ad2v, float b2v,
                                          float* __restrict__ out) {
    int d0 = rcA.y, d1 = rcA.w, d2 = rcB.y, d3 = rcB.w;
    if (d0 <= 32 && d1 <= 32 && d2 <= 32 && d3 <= 32) {
        int half = lane >> 5, li = lane & 31;
        int nA = n0 + half, nB = n0 + 2 + half;
        int offA = half ? rcA.z : rcA.x;
        int offB = half ? rcB.z : rcB.x;
        int degA = half ? d1 : d0, degB = half ? d3 : d2;
        float sdA = h2[nA] * ad2v, sdB = h2[nB] * ad2v;
        float hvA = 0.f, hvB = 0.f, pA = 0.f, pB = 0.f;
        if (li < degA) {
            hvA = h2[adj[offA + li]];
            float t = hvA * as2v + sdA;
            pA = __expf(t > 0.f ? t : NEG * t);
        }
        if (li < degB) {
            hvB = h2[adj[offB + li]];
            float t = hvB * as2v + sdB;
            pB = __expf(t > 0.f ? t : NEG * t);
        }
        float dsA = pA, dsB = pB, nsA = pA * hvA, nsB = pB * hvB;
#pragma unroll
        for (int o = 1; o <= 16; o <<= 1) {
            dsA += __shfl_xor(dsA, o); nsA += __shfl_xor(nsA, o);
            dsB += __shfl_xor(dsB, o); nsB += __shfl_xor(nsB, o);
        }
        if (li == 0) {
            out[nA] = nsA / dsA + b2v;
            out[nB] = nsB / dsB + b2v;
        }
    } else {
        for (int w = 0; w < 4; ++w) {
            int n = n0 + w;
            int off = (w == 0) ? rcA.x : (w == 1) ? rcA.z : (w == 2) ? rcB.x : rcB.z;
            int deg = (w == 0) ? d0 : (w == 1) ? d1 : (w == 2) ? d2 : d3;
            float sdn = h2[n] * ad2v;
            float dsum = 0.f, nsum = 0.f;
            for (int j0 = 0; j0 < deg; j0 += 64) {
                int j = j0 + lane;
                if (j < deg) {
                    int s = adj[off + j];
                    float hv = h2[s];
                    float e = hv * as2v + sdn;
                    e = e > 0.f ? e : NEG * e;
                    float ex = __expf(e);
                    dsum += ex;
                    nsum += ex * hv;
                }
            }
#pragma unroll
            for (int o = 32; o; o >>= 1) { dsum += __shfl_xor(dsum, o); nsum += __shfl_xor(nsum, o); }
            if (lane == 0) out[n] = nsum / dsum + b2v;
        }
    }
}

// ==================== LDS layouts ====================
struct ScatterLDS {
    unsigned sp[SCT_TILE];
    unsigned short bid[SCT_TILE];
    int cnt_[NBUK], loc[NBUK], cur[NBUK];
    int wsum[16];
};
struct BsortLDS {
    int srt[BUKCAP];
    int hist[256], scn[256];
};

// ==================== cooperative mega-kernel ====================
__global__ __launch_bounds__(TPB, 2) void k_mega(const float* __restrict__ x,
                                                 const float* __restrict__ W1,
                                                 const float* __restrict__ a_src1,
                                                 const float* __restrict__ a_dst1,
                                                 const int* __restrict__ ei,
                                                 const float* __restrict__ b1,
                                                 const float* __restrict__ W2,
                                                 const float* __restrict__ as2,
                                                 const float* __restrict__ ad2,
                                                 const float* __restrict__ b2,
                                                 unsigned* __restrict__ rec,
                                                 float* __restrict__ sd1,
                                                 int* __restrict__ bcur,
                                                 unsigned* __restrict__ pairs,
                                                 int2* __restrict__ rowcnt,
                                                 float* __restrict__ h2,
                                                 float* __restrict__ out) {
    cg::grid_group grid = cg::this_grid();
    __shared__ union { ScatterLDS sc; BsortLDS bs; } sh;
    int tid = threadIdx.x;
    int wid = tid >> 6, lane = tid & 63;
    int bx = blockIdx.x;
    int GS = gridDim.x;
    int* adj = (int*)pairs;

    // phase 0: zero bcur
    for (int i = bx * TPB + tid; i < 1024; i += GS * TPB) bcur[i] = 0;
    grid.sync();

    // phase 1: scatter tiles + proj quanta
    for (int q = bx; q < NSCT + NPROJQ; q += GS) {
        if (q < NSCT)
            scatter_tile(sh.sc, q, tid, wid, lane, ei, bcur, pairs);
        else
            proj_quantum(q - NSCT, tid, wid, x, W1, a_src1, a_dst1, rec, sd1);
    }
    grid.sync();

    // phase 2: per-bucket counting sort
    for (int b = bx; b < NBUK; b += GS)
        bsort_bucket(sh.bs, b, tid, bcur, pairs, rowcnt);
    grid.sync();

    // phase 3: layer-1 aggregate (16 waves x 2 nodes per quantum)
    const int* rc32 = (const int*)rowcnt;
    for (int q = bx; q < NAGG1Q; q += GS) {
        int n0 = q * 32 + wid * 2;
        if (n0 >= NN) continue;
        const int4 rc = *(const int4*)(rc32 + n0 * 2);
        agg1_pair(n0, lane, rc, adj, rec, sd1, W1, b1, W2, h2);
    }
    grid.sync();

    // phase 4: layer-2 aggregate (16 waves x 4 nodes per quantum)
    float as2v = as2[0], ad2v = ad2[0], b2v = b2[0];
    for (int q = bx; q < NAGG2Q; q += GS) {
        int n0 = q * 64 + wid * 4;
        if (n0 >= NN) continue;
        const int4 rcA = *(const int4*)(rc32 + n0 * 2);
        const int4 rcB = *(const int4*)(rc32 + n0 * 2 + 4);
        agg2_quad(n0, lane, rcA, rcB, adj, h2, as2v, ad2v, b2v, out);
    }
}

// ==================== fallback pipeline (R21/R23-proven) ====================
#define NPROJB ((NN + 31) / 32)

__global__ __launch_bounds__(TPB) void f_front(const float* __restrict__ x,
                                               const float* __restrict__ W1,
                                               const float* __restrict__ a_src1,
                                               const float* __restrict__ a_dst1,
                                               const int* __restrict__ ei,
                                               unsigned* __restrict__ rec,
                                               float* __restrict__ sd1,
                                               int* __restrict__ bcur,
                                               unsigned* __restrict__ pairs) {
    __shared__ ScatterLDS sc;
    int tid = threadIdx.x;
    int wid = tid >> 6, lane = tid & 63;
    if (blockIdx.x >= NSCT) {
        proj_quantum(blockIdx.x - NSCT, tid, wid, x, W1, a_src1, a_dst1, rec, sd1);
        return;
    }
    scatter_tile(sc, blockIdx.x, tid, wid, lane, ei, bcur, pairs);
}

__global__ __launch_bounds__(TPB) void f_bsort(const int* __restrict__ bcur,
                                               unsigned* __restrict__ pairs,
                                               int2* __restrict__ rowcnt) {
    __shared__ BsortLDS bs;
    bsort_bucket(bs, blockIdx.x, threadIdx.x, bcur, pairs, rowcnt);
}

__global__ __launch_bounds__(256) void f_agg1(const int* __restrict__ rowcnt,
                                              const int* __restrict__ adj,
                                              const unsigned* __restrict__ rec,
                                              const float* __restrict__ sd1,
                                              const float* __restrict__ W1,
                                              const float* __restrict__ b1,
                                              const float* __restrict__ W2,
                                              float* __restrict__ h2) {
    int wid  = threadIdx.x >> 6;
    int lane = threadIdx.x & 63;
    int n0 = (blockIdx.x * 4 + wid) * 2;
    if (n0 >= NN) return;
    const int4 rc = *(const int4*)(rowcnt + n0 * 2);
    agg1_pair(n0, lane, rc, adj, rec, sd1, W1, b1, W2, h2);
}

__global__ __launch_bounds__(256) void f_agg2(const int* __restrict__ rowcnt,
                                              const int* __restrict__ adj,
                                              const float* __restrict__ h2,
                                              const float* __restrict__ as2,
                                              const float* __restrict__ ad2,
                                              const float* __restrict__ b2,
                                              float* __restrict__ out) {
    int wid  = threadIdx.x >> 6;
    int lane = threadIdx.x & 63;
    int n0 = (blockIdx.x * 4 + wid) * 4;
    if (n0 >= NN) return;
    const int4 rcA = *(const int4*)(rowcnt + n0 * 2);
    const int4 rcB = *(const int4*)(rowcnt + n0 * 2 + 4);
    agg2_quad(n0, lane, rcA, rcB, adj, h2, as2[0], ad2[0], b2[0], out);
}

extern "C" void kernel_launch(void* const* d_in, const int* in_sizes, int n_in,
                              void* d_out, int out_size, void* d_ws, size_t ws_size,
                              hipStream_t stream) {
    const float* x      = (const float*)d_in[0];
    const int*   ei     = (const int*)d_in[1];
    const float* W1     = (const float*)d_in[2];
    const float* a_src1 = (const float*)d_in[3];
    const float* a_dst1 = (const float*)d_in[4];
    const float* b1     = (const float*)d_in[5];
    const float* W2     = (const float*)d_in[6];
    const float* as2    = (const float*)d_in[7];
    const float* ad2    = (const float*)d_in[8];
    const float* b2     = (const float*)d_in[9];
    float* out = (float*)d_out;

    // workspace layout (all 4-byte elements)
    unsigned* rec = (unsigned*)d_ws;                    // N*4 words = 1.6MB
    float* sd1  = (float*)(rec + (size_t)NN * 4);       // N
    float* h2   = sd1 + NN;                             // N
    int2* rowcnt = (int2*)(h2 + NN);                    // N int2
    int* bcur   = (int*)(rowcnt + NN);                  // 1024
    unsigned* pairs = (unsigned*)(bcur + 1024);         // NBUK*BUKCAP = 12.8MB (reused as adj)
    int* adj    = (int*)pairs;

    // ---- try cooperative mega-kernel with occupancy-derived grid ----
    bool done = false;
    int dev = 0;
    if (hipGetDevice(&dev) == hipSuccess) {
        int coop = 0, ncu = 0, maxB = 0;
        hipDeviceGetAttribute(&coop, hipDeviceAttributeCooperativeLaunch, dev);
        hipDeviceGetAttribute(&ncu, hipDeviceAttributeMultiprocessorCount, dev);
        hipError_t oe = hipOccupancyMaxActiveBlocksPerMultiprocessor(
                            &maxB, (const void*)k_mega, TPB, 0);
        if (coop && oe == hipSuccess && maxB > 0 && ncu > 0) {
            int g = maxB * ncu;
            if (g > 512) g = 512;
            void* args[] = {
                (void*)&x, (void*)&W1, (void*)&a_src1, (void*)&a_dst1, (void*)&ei,
                (void*)&b1, (void*)&W2, (void*)&as2, (void*)&ad2, (void*)&b2,
                (void*)&rec, (void*)&sd1, (void*)&bcur, (void*)&pairs, (void*)&rowcnt,
                (void*)&h2, (void*)&out
            };
            hipError_t le = hipLaunchCooperativeKernel((const void*)k_mega, dim3(g),
                                                       dim3(TPB), args, 0, stream);
            if (le == hipSuccess) done = true;
            else (void)hipGetLastError();   // clear error state
        }
    }

    if (!done) {
        // ---- fallback: proven 4-kernel pipeline (~70.5us) ----
        const int NPAIR = (NN / 2 + 3) / 4;
        const int NQUAD = (NN + 15) / 16;
        hipMemsetAsync(bcur, 0, 1024 * sizeof(int), stream);
        f_front<<<NSCT + NPROJB, TPB, 0, stream>>>(x, W1, a_src1, a_dst1, ei,
                                                   rec, sd1, bcur, pairs);
        f_bsort<<<NBUK, TPB, 0, stream>>>(bcur, pairs, rowcnt);
        f_agg1<<<NPAIR, 256, 0, stream>>>((const int*)rowcnt, adj, rec, sd1, W1, b1, W2, h2);
        f_agg2<<<NQUAD, 256, 0, stream>>>((const int*)rowcnt, adj, h2, as2, ad2, b2, out);
    }
}

// Round 26
// 70.458 us; speedup vs baseline: 1.1012x; 1.0015x over previous
//
#include <hip/hip_runtime.h>
#include <hip/hip_bf16.h>
#include <hip/hip_fp16.h>

#define NN 100000
#define EE 1600000
#define ET (EE + NN)            // edges incl. self loops
#define HID 64
#define NEG 0.2f
#define NBUK 391                // ceil(NN/256) buckets of 256 dst nodes
#define SCT_TILE 8192           // edges per block in scatter phase (1024 thr x 8)
#define BUKCAP 8192             // padded per-bucket capacity (mean 4352, sigma~66)

__device__ __forceinline__ float uh(unsigned u) {
    __half_raw r; r.x = (unsigned short)(u & 0xFFFF);
    return __half2float(__half(r));
}
__device__ __forceinline__ unsigned f2h(float f) {
    __half h = __float2half_rn(f);
    __half_raw r = *reinterpret_cast<__half_raw*>(&h);
    return (unsigned)r.x;
}

#define NSCT ((ET + SCT_TILE - 1) / SCT_TILE)   // 208 scatter-role blocks
#define NPROJB ((NN + 31) / 32)                 // 3125 proj-role blocks (32 nodes each)

// ---------------- merged front kernel: scatter role (blocks < NSCT) + proj role ----------------
__global__ __launch_bounds__(1024) void k_front(const float* __restrict__ x,
                                                const float* __restrict__ W1,
                                                const float* __restrict__ a_src1,
                                                const float* __restrict__ a_dst1,
                                                const int* __restrict__ ei,
                                                unsigned* __restrict__ rec,
                                                float* __restrict__ sd1,
                                                int* __restrict__ bcur,
                                                unsigned* __restrict__ pairs) {
    __shared__ unsigned sp[SCT_TILE];
    __shared__ unsigned short bid[SCT_TILE];
    __shared__ int cnt_[NBUK], loc[NBUK], cur[NBUK];
    __shared__ int wsum[16];
    int tid = threadIdx.x;

    if (blockIdx.x >= NSCT) {
        // ---- proj role: 16 waves x 2 nodes = 32 nodes per block ----
        int p = blockIdx.x - NSCT;
        int wid  = tid >> 6;
        int half = (tid >> 5) & 1, li = tid & 31;
        int n = p * 32 + wid * 2 + half;
        if (n >= NN) return;
        float xv[5];
        float h0 = 0.f, h1 = 0.f;
#pragma unroll
        for (int k = 0; k < 5; ++k) {
            xv[k] = x[n * 5 + k];
            h0 += xv[k] * W1[k * HID + li];
            h1 += xv[k] * W1[k * HID + li + 32];
        }
        float a = h0 * a_src1[li] + h1 * a_src1[li + 32];
        float b = h0 * a_dst1[li] + h1 * a_dst1[li + 32];
#pragma unroll
        for (int o = 1; o <= 16; o <<= 1) { a += __shfl_xor(a, o); b += __shfl_xor(b, o); }
        if (li == 0) {
            sd1[n] = b;
            uint4 rv;
            rv.x = __float_as_uint(a);
            rv.y = f2h(xv[0]) | (f2h(xv[1]) << 16);
            rv.z = f2h(xv[2]) | (f2h(xv[3]) << 16);
            rv.w = f2h(xv[4]);
            *(uint4*)(rec + (size_t)n * 4) = rv;
        }
        return;
    }

    // ---- scatter role ----
    int wid = tid >> 6, lane = tid & 63;
    int base = blockIdx.x * SCT_TILE;
    int tilecnt = ET - base; if (tilecnt > SCT_TILE) tilecnt = SCT_TILE;

    for (int i = tid; i < NBUK; i += 1024) cnt_[i] = 0;
    __syncthreads();
    int sreg[8], dreg[8], rreg[8];
#pragma unroll
    for (int it = 0; it < 2; ++it) {
        int i = base + (it * 1024 + tid) * 4;
        if (i + 3 < EE) {
            const int4 sv = *(const int4*)(ei + i);
            const int4 dv = *(const int4*)(ei + EE + i);
            sreg[it*4+0] = sv.x; sreg[it*4+1] = sv.y; sreg[it*4+2] = sv.z; sreg[it*4+3] = sv.w;
            dreg[it*4+0] = dv.x; dreg[it*4+1] = dv.y; dreg[it*4+2] = dv.z; dreg[it*4+3] = dv.w;
        } else {
#pragma unroll
            for (int k = 0; k < 4; ++k) {
                int idx = i + k;
                if (idx < EE)      { sreg[it*4+k] = ei[idx];  dreg[it*4+k] = ei[EE + idx]; }
                else if (idx < ET) { sreg[it*4+k] = idx - EE; dreg[it*4+k] = idx - EE; }
                else               { dreg[it*4+k] = -1; }
            }
        }
#pragma unroll
        for (int k = 0; k < 4; ++k)
            if (dreg[it*4+k] >= 0) rreg[it*4+k] = atomicAdd(&cnt_[dreg[it*4+k] >> 8], 1);
    }
    __syncthreads();
    int b0 = tid * 4;
    int s0 = 0;
    if (b0 < NBUK)
        for (int k = 0; k < 4 && b0 + k < NBUK; ++k) s0 += cnt_[b0 + k];
    int incl = s0;
#pragma unroll
    for (int o = 1; o < 64; o <<= 1) {
        int t = __shfl(incl, (lane - o) & 63);
        if (lane >= o) incl += t;
    }
    if (lane == 63) wsum[wid] = incl;
    __syncthreads();
    int wpref = 0;
    for (int w = 0; w < wid; ++w) wpref += wsum[w];
    if (b0 < NBUK) {
        int run = wpref + incl - s0;
        for (int k = 0; k < 4 && b0 + k < NBUK; ++k) {
            loc[b0 + k] = run;
            run += cnt_[b0 + k];
        }
    }
    __syncthreads();
    for (int i = tid; i < NBUK; i += 1024) {
        int c = cnt_[i];
        cur[i] = c ? (atomicAdd(&bcur[i], c) + i * BUKCAP - loc[i]) : 0;
    }
    __syncthreads();
#pragma unroll
    for (int q = 0; q < 8; ++q) {
        if (dreg[q] >= 0) {
            int s = sreg[q], d = dreg[q];
            int b = d >> 8;
            int slot = loc[b] + rreg[q];
            sp[slot]  = ((unsigned)(d & 255) << 17) | (unsigned)s;
            bid[slot] = (unsigned short)b;
        }
    }
    __syncthreads();
    for (int i = tid; i < tilecnt; i += 1024)
        pairs[cur[bid[i]] + i] = sp[i];
}

// ---------------- per-bucket counting sort: LDS-staged sort, CONTIGUOUS adj flush ----------------
__global__ __launch_bounds__(1024) void k_bsort(const int* __restrict__ bcur,
                                                unsigned* __restrict__ pairs,
                                                int2* __restrict__ rowcnt) {
    __shared__ int srt[BUKCAP];     // 32KB sorted srcs
    __shared__ int hist[256], sc[256];
    int b = blockIdx.x;
    int cnt = bcur[b];
    if (cnt > BUKCAP) cnt = BUKCAP;
    int base = b * BUKCAP;
    int tid = threadIdx.x;
    if (tid < 256) hist[tid] = 0;
    __syncthreads();
    // pass 1: vectorized read (8 contiguous pairs/thread), rank-atomic, registers
    unsigned preg[8];
    int rreg[8];
    int i0 = tid * 8;
    if (i0 + 8 <= cnt) {
        const uint4 v0 = *(const uint4*)(pairs + base + i0);
        const uint4 v1 = *(const uint4*)(pairs + base + i0 + 4);
        preg[0] = v0.x; preg[1] = v0.y; preg[2] = v0.z; preg[3] = v0.w;
        preg[4] = v1.x; preg[5] = v1.y; preg[6] = v1.z; preg[7] = v1.w;
    } else {
#pragma unroll
        for (int j = 0; j < 8; ++j)
            preg[j] = (i0 + j < cnt) ? pairs[base + i0 + j] : 0xFFFFFFFFu;
    }
#pragma unroll
    for (int j = 0; j < 8; ++j)
        if (preg[j] != 0xFFFFFFFFu) rreg[j] = atomicAdd(&hist[preg[j] >> 17], 1);
    __syncthreads();
    // 256-bin exclusive scan on wave 0 (4 bins/lane)
    if (tid < 64) {
        int v0 = hist[4 * tid], v1 = hist[4 * tid + 1];
        int v2 = hist[4 * tid + 2], v3 = hist[4 * tid + 3];
        int s = v0 + v1 + v2 + v3;
#pragma unroll
        for (int o = 1; o < 64; o <<= 1) {
            int t = __shfl(s, (tid - o) & 63);
            if (tid >= o) s += t;
        }
        int excl = s - v0 - v1 - v2 - v3;
        sc[4 * tid]     = excl;
        sc[4 * tid + 1] = excl + v0;
        sc[4 * tid + 2] = excl + v0 + v1;
        sc[4 * tid + 3] = excl + v0 + v1 + v2;
    }
    __syncthreads();
    int nbase = b << 8;
    if (tid < 256 && nbase + tid < NN)
        rowcnt[nbase + tid] = make_int2(base + sc[tid], hist[tid]);
    // scatter into LDS (cheap: <=2-way bank aliasing), then flush contiguously
#pragma unroll
    for (int j = 0; j < 8; ++j) {
        if (preg[j] != 0xFFFFFFFFu) {
            int ld = (int)(preg[j] >> 17);
            srt[sc[ld] + rreg[j]] = (int)(preg[j] & 0x1FFFF);
        }
    }
    __syncthreads();
    int* adj = (int*)pairs;   // aliases pairs; all pairs reads completed above
    for (int i = tid; i < cnt; i += 1024)
        adj[base + i] = srt[i];
}

// ---------------- layer 1 generic fallback (deg>32): single pass, no max, 16B record ----------------
__device__ __forceinline__ void agg1_node_gen(int n, int lane, int off, int deg,
                                              const int* __restrict__ adj,
                                              const unsigned* __restrict__ rec,
                                              const float* __restrict__ sd1,
                                              const float* __restrict__ W1,
                                              const float* __restrict__ b1,
                                              const float* __restrict__ W2,
                                              float* __restrict__ h2) {
    float sdn = sd1[n];
    float dsum = 0.f, a0 = 0.f, a1 = 0.f, a2 = 0.f, a3 = 0.f, a4 = 0.f;
    for (int j0 = 0; j0 < deg; j0 += 64) {
        int j = j0 + lane;
        if (j < deg) {
            int s = adj[off + j];
            const uint4 v = *(const uint4*)(rec + (size_t)s * 4);
            float t = __uint_as_float(v.x) + sdn;
            float e = t > 0.f ? t : NEG * t;
            float w = __expf(e);
            dsum += w;
            a0 += w * uh(v.y); a1 += w * uh(v.y >> 16);
            a2 += w * uh(v.z); a3 += w * uh(v.z >> 16);
            a4 += w * uh(v.w);
        }
    }
#pragma unroll
    for (int o = 32; o; o >>= 1) {
        dsum += __shfl_xor(dsum, o);
        a0 += __shfl_xor(a0, o); a1 += __shfl_xor(a1, o); a2 += __shfl_xor(a2, o);
        a3 += __shfl_xor(a3, o); a4 += __shfl_xor(a4, o);
    }
    float inv = 1.0f / dsum;
    a0 *= inv; a1 *= inv; a2 *= inv; a3 *= inv; a4 *= inv;
    float of = b1[lane] + a0 * W1[lane] + a1 * W1[64 + lane] + a2 * W1[128 + lane]
             + a3 * W1[192 + lane] + a4 * W1[256 + lane];
    of = fmaxf(of, 0.f);
    float p2 = of * W2[lane];
#pragma unroll
    for (int o = 32; o; o >>= 1) p2 += __shfl_xor(p2, o);
    if (lane == 0) h2[n] = p2;
}

// ---------------- layer 1: lane=edge, 2 nodes per wave, no max, ONE 16B gather/edge ----------------
__global__ __launch_bounds__(256) void k_agg1(const int* __restrict__ rowcnt,
                                              const int* __restrict__ adj,
                                              const unsigned* __restrict__ rec,
                                              const float* __restrict__ sd1,
                                              const float* __restrict__ W1,
                                              const float* __restrict__ b1,
                                              const float* __restrict__ W2,
                                              float* __restrict__ h2) {
    int wid  = threadIdx.x >> 6;
    int lane = threadIdx.x & 63;
    int n0 = (blockIdx.x * 4 + wid) * 2;
    if (n0 >= NN) return;
    const int4 rc = *(const int4*)(rowcnt + n0 * 2);
    int off0 = rc.x, d0 = rc.y, off1 = rc.z, d1 = rc.w;

    if (d0 <= 32 && d1 <= 32) {
        int half = lane >> 5, li = lane & 31;
        int n = n0 + half;
        int off = half ? off1 : off0;
        int deg = half ? d1 : d0;
        float sdn = sd1[n];
        int s = adj[off + (li < deg ? li : 0)];
        const uint4 v = *(const uint4*)(rec + (size_t)s * 4);
        float t = __uint_as_float(v.x) + sdn;
        float e = t > 0.f ? t : NEG * t;
        float p = (li < deg) ? __expf(e) : 0.f;
        float ds = p;
        float a0 = p * uh(v.y), a1 = p * uh(v.y >> 16);
        float a2 = p * uh(v.z), a3 = p * uh(v.z >> 16);
        float a4 = p * uh(v.w);
#pragma unroll
        for (int o = 1; o <= 16; o <<= 1) {
            ds += __shfl_xor(ds, o);
            a0 += __shfl_xor(a0, o); a1 += __shfl_xor(a1, o); a2 += __shfl_xor(a2, o);
            a3 += __shfl_xor(a3, o); a4 += __shfl_xor(a4, o);
        }
        float inv = 1.0f / ds;
        a0 *= inv; a1 *= inv; a2 *= inv; a3 *= inv; a4 *= inv;
        float o0 = b1[li] + a0 * W1[li] + a1 * W1[64 + li] + a2 * W1[128 + li]
                 + a3 * W1[192 + li] + a4 * W1[256 + li];
        float o1 = b1[li + 32] + a0 * W1[li + 32] + a1 * W1[96 + li] + a2 * W1[160 + li]
                 + a3 * W1[224 + li] + a4 * W1[288 + li];
        o0 = fmaxf(o0, 0.f);
        o1 = fmaxf(o1, 0.f);
        float p2 = o0 * W2[li] + o1 * W2[li + 32];
#pragma unroll
        for (int o = 1; o <= 16; o <<= 1) p2 += __shfl_xor(p2, o);
        if (li == 0) h2[n] = p2;
    } else {
        agg1_node_gen(n0,     lane, off0, d0, adj, rec, sd1, W1, b1, W2, h2);
        agg1_node_gen(n0 + 1, lane, off1, d1, adj, rec, sd1, W1, b1, W2, h2);
    }
}

// ---------------- layer 2: full-wave single-node fallback (no max, single pass) ----------------
__device__ __forceinline__ void agg2_node(int n, int lane, int off, int deg,
                                          const int* __restrict__ adj,
                                          const float* __restrict__ h2,
                                          float as2v, float ad2v, float b2v,
                                          float* __restrict__ out) {
    float sdn = h2[n] * ad2v;
    float dsum = 0.f, nsum = 0.f;
    for (int j0 = 0; j0 < deg; j0 += 64) {
        int j = j0 + lane;
        if (j < deg) {
            int s = adj[off + j];
            float hv = h2[s];
            float e = hv * as2v + sdn;
            e = e > 0.f ? e : NEG * e;
            float ex = __expf(e);
            dsum += ex;
            nsum += ex * hv;
        }
    }
#pragma unroll
    for (int o = 32; o; o >>= 1) { dsum += __shfl_xor(dsum, o); nsum += __shfl_xor(nsum, o); }
    if (lane == 0) out[n] = nsum / dsum + b2v;
}

// ---------------- layer 2: 4 nodes per wave, no max ----------------
__global__ __launch_bounds__(256) void k_agg2(const int* __restrict__ rowcnt,
                                              const int* __restrict__ adj,
                                              const float* __restrict__ h2,
                                              const float* __restrict__ as2,
                                              const float* __restrict__ ad2,
                                              const float* __restrict__ b2,
                                              float* __restrict__ out) {
    int wid  = threadIdx.x >> 6;
    int lane = threadIdx.x & 63;
    int n0 = (blockIdx.x * 4 + wid) * 4;
    if (n0 >= NN) return;
    float as2v = as2[0], ad2v = ad2[0], b2v = b2[0];
    const int4 rcA = *(const int4*)(rowcnt + n0 * 2);
    const int4 rcB = *(const int4*)(rowcnt + n0 * 2 + 4);
    int d0 = rcA.y, d1 = rcA.w, d2 = rcB.y, d3 = rcB.w;

    if (d0 <= 32 && d1 <= 32 && d2 <= 32 && d3 <= 32) {
        int half = lane >> 5, li = lane & 31;
        int nA = n0 + half, nB = n0 + 2 + half;
        int offA = half ? rcA.z : rcA.x;
        int offB = half ? rcB.z : rcB.x;
        int degA = half ? d1 : d0, degB = half ? d3 : d2;
        float sdA = h2[nA] * ad2v, sdB = h2[nB] * ad2v;
        float hvA = 0.f, hvB = 0.f, pA = 0.f, pB = 0.f;
        if (li < degA) {
            hvA = h2[adj[offA + li]];
            float t = hvA * as2v + sdA;
            pA = __expf(t > 0.f ? t : NEG * t);
        }
        if (li < degB) {
            hvB = h2[adj[offB + li]];
            float t = hvB * as2v + sdB;
            pB = __expf(t > 0.f ? t : NEG * t);
        }
        float dsA = pA, dsB = pB, nsA = pA * hvA, nsB = pB * hvB;
#pragma unroll
        for (int o = 1; o <= 16; o <<= 1) {
            dsA += __shfl_xor(dsA, o); nsA += __shfl_xor(nsA, o);
            dsB += __shfl_xor(dsB, o); nsB += __shfl_xor(nsB, o);
        }
        if (li == 0) {
            out[nA] = nsA / dsA + b2v;
            out[nB] = nsB / dsB + b2v;
        }
    } else {
        agg2_node(n0,     lane, rcA.x, d0, adj, h2, as2v, ad2v, b2v, out);
        agg2_node(n0 + 1, lane, rcA.z, d1, adj, h2, as2v, ad2v, b2v, out);
        agg2_node(n0 + 2, lane, rcB.x, d2, adj, h2, as2v, ad2v, b2v, out);
        agg2_node(n0 + 3, lane, rcB.z, d3, adj, h2, as2v, ad2v, b2v, out);
    }
}

extern "C" void kernel_launch(void* const* d_in, const int* in_sizes, int n_in,
                              void* d_out, int out_size, void* d_ws, size_t ws_size,
                              hipStream_t stream) {
    const float* x      = (const float*)d_in[0];
    const int*   ei     = (const int*)d_in[1];
    const float* W1     = (const float*)d_in[2];
    const float* a_src1 = (const float*)d_in[3];
    const float* a_dst1 = (const float*)d_in[4];
    const float* b1     = (const float*)d_in[5];
    const float* W2     = (const float*)d_in[6];
    const float* as2    = (const float*)d_in[7];
    const float* ad2    = (const float*)d_in[8];
    const float* b2     = (const float*)d_in[9];
    float* out = (float*)d_out;

    // workspace layout (all 4-byte elements)
    unsigned* rec = (unsigned*)d_ws;                    // N*4 words = 1.6MB
    float* sd1  = (float*)(rec + (size_t)NN * 4);       // N
    float* h2   = sd1 + NN;                             // N
    int2* rowcnt = (int2*)(h2 + NN);                    // N int2 (16B-aligned pairs)
    int* bcur   = (int*)(rowcnt + NN);                  // 1024
    unsigned* pairs = (unsigned*)(bcur + 1024);         // NBUK*BUKCAP = 12.8MB (reused as adj)
    int* adj    = (int*)pairs;

    const int NPAIR = (NN / 2 + 3) / 4;                 // 12500 blocks, 2 nodes/wave
    const int NQUAD = (NN + 15) / 16;                   // 6250 blocks, 4 nodes/wave

    hipMemsetAsync(bcur, 0, 1024 * sizeof(int), stream);
    k_front<<<NSCT + NPROJB, 1024, 0, stream>>>(x, W1, a_src1, a_dst1, ei,
                                                rec, sd1, bcur, pairs);
    k_bsort<<<NBUK, 1024, 0, stream>>>(bcur, pairs, rowcnt);
    k_agg1<<<NPAIR, 256, 0, stream>>>((const int*)rowcnt, adj, rec, sd1, W1, b1, W2, h2);
    k_agg2<<<NQUAD, 256, 0, stream>>>((const int*)rowcnt, adj, h2, as2, ad2, b2, out);
}